// Round 20
// baseline (1211.265 us; speedup 1.0000x reference)
//
#include <hip/hip_runtime.h>

typedef unsigned short u16;
typedef unsigned int u32;
typedef float f32x4 __attribute__((ext_vector_type(4)));
typedef float f32x16 __attribute__((ext_vector_type(16)));
typedef __bf16 bf16x8 __attribute__((ext_vector_type(8)));
typedef short short8 __attribute__((ext_vector_type(8)));
typedef u32 u32x4 __attribute__((ext_vector_type(4)));

#define DINLINE static __device__ __forceinline__

// ---------- helpers ----------
DINLINE u16 f2bf(float f) {  // RNE float->bf16
  u32 u = __builtin_bit_cast(u32, f);
  u += 0x7fffu + ((u >> 16) & 1u);
  return (u16)(u >> 16);
}

DINLINE float b2f(u32 lo16) {  // low 16 bits = bf16
  u32 u = lo16 << 16;
  return __builtin_bit_cast(float, u);
}

DINLINE f32x4 mfma16(short8 a, short8 b, f32x4 c) {
  return __builtin_amdgcn_mfma_f32_16x16x32_bf16(
      __builtin_bit_cast(bf16x8, a), __builtin_bit_cast(bf16x8, b), c, 0, 0, 0);
}

DINLINE f32x16 mfma32(short8 a, short8 b, f32x16 c) {
  return __builtin_amdgcn_mfma_f32_32x32x16_bf16(
      __builtin_bit_cast(bf16x8, a), __builtin_bit_cast(bf16x8, b), c, 0, 0, 0);
}

DINLINE u32 cvtpk(float lo, float hi) {
  u32 r;
  asm("v_cvt_pk_bf16_f32 %0, %1, %2" : "=v"(r) : "v"(lo), "v"(hi));
  return r;
}

DINLINE void plswap(u32& a, u32& b) {
  auto r = __builtin_amdgcn_permlane32_swap(a, b, false, false);
  a = (u32)r[0];
  b = (u32)r[1];
}

DINLINE void gld16(const void* g, void* l) {
  __builtin_amdgcn_global_load_lds(
      (const __attribute__((address_space(1))) void*)g,
      (__attribute__((address_space(3))) void*)l, 16, 0, 0);
}

// ---------- batched 1024x1024 weight transpose (8 matrices in one dispatch) ----------
struct W8 {
  const float* src[8];
  u16* dst[8];
  float scale[8];
};
__global__ __launch_bounds__(256) void transpose_wt8(W8 p) {
  __shared__ float tile[32][33];
  const int z = blockIdx.z;
  const float* __restrict__ src = p.src[z];
  u16* __restrict__ dst = p.dst[z];
  const float scale = p.scale[z];
  int n0 = blockIdx.x * 32, k0 = blockIdx.y * 32;
  int tx = threadIdx.x, ty = threadIdx.y;  // 32 x 8
#pragma unroll
  for (int j = 0; j < 32; j += 8)
    tile[ty + j][tx] = src[(size_t)(k0 + ty + j) * 1024 + n0 + tx];
  __syncthreads();
#pragma unroll
  for (int j = 0; j < 32; j += 8)
    dst[(size_t)(n0 + ty + j) * 1024 + k0 + tx] = f2bf(tile[tx][ty + j] * scale);
}

// ---------- weight transpose+convert: src fp32 [K][N] -> dst bf16 [N][K] (x scale) ----------
__global__ __launch_bounds__(256) void transpose_wt(const float* __restrict__ src,
                                                    u16* __restrict__ dst, int K, int N,
                                                    float scale) {
  __shared__ float tile[32][33];
  int n0 = blockIdx.x * 32, k0 = blockIdx.y * 32;
  int tx = threadIdx.x, ty = threadIdx.y;  // 32 x 8
#pragma unroll
  for (int j = 0; j < 32; j += 8)
    tile[ty + j][tx] = src[(size_t)(k0 + ty + j) * N + n0 + tx];
  __syncthreads();
#pragma unroll
  for (int j = 0; j < 32; j += 8)
    dst[(size_t)(n0 + ty + j) * K + k0 + tx] = f2bf(tile[tx][ty + j] * scale);
}

// ---------- fp32 -> bf16 elementwise (4/thread) ----------
__global__ __launch_bounds__(256) void cvt_bf16(const float* __restrict__ src,
                                                u16* __restrict__ dst) {
  size_t i = (size_t)blockIdx.x * 256 + threadIdx.x;
  float4 v = ((const float4*)src)[i];
  u32 lo = (u32)f2bf(v.x) | ((u32)f2bf(v.y) << 16);
  u32 hi = (u32)f2bf(v.z) | ((u32)f2bf(v.w) << 16);
  uint2 o; o.x = lo; o.y = hi;
  ((uint2*)dst)[i] = o;
}

// ---------- bias prep: b_qkv[3072] (q scaled) and b_xaq[1024] in one dispatch ----------
__global__ void prep_bias(const float* __restrict__ a, const float* __restrict__ b,
                          const float* __restrict__ c, const float* __restrict__ xq,
                          float* __restrict__ oqkv, float* __restrict__ oxq, float sa) {
  int i = blockIdx.x * 256 + threadIdx.x;  // 4096 total
  if (i < 1024) oqkv[i] = a[i] * sa;
  else if (i < 2048) oqkv[i] = b[i - 1024];
  else if (i < 3072) oqkv[i] = c[i - 2048];
  else oxq[i - 3072] = xq[i - 3072] * sa;
}

// ---------- positional-encoding table pe[s][c], s<1024 ----------
__global__ __launch_bounds__(256) void pe_k(float* __restrict__ pe) {
  int s = blockIdx.x;
  for (int c = threadIdx.x; c < 1024; c += 256) {
    int i = c >> 1;
    float den = expf(-(float)(2 * i) * 0.0089944739960705f);  // ln(10000)/1024
    float ang = (float)s * den;
    pe[s * 1024 + c] = (c & 1) ? cosf(ang) : sinf(ang);
  }
}

// ---------- embedding * sqrt(d) + PE table; writes fp32 x and bf16 copy ----------
__global__ __launch_bounds__(256) void embed_pe(const int* __restrict__ tgt,
                                                const float* __restrict__ emb,
                                                const float* __restrict__ pe,
                                                float* __restrict__ x,
                                                u16* __restrict__ xbf) {
  int row = blockIdx.x;  // b*1024 + s
  int s = row & 1023;
  int tok = tgt[row];
  float4 e = ((const float4*)(emb + (size_t)tok * 1024))[threadIdx.x];
  float4 p = ((const float4*)(pe + (size_t)s * 1024))[threadIdx.x];
  float4 o;
  o.x = e.x * 32.0f + p.x; o.y = e.y * 32.0f + p.y;
  o.z = e.z * 32.0f + p.z; o.w = e.w * 32.0f + p.w;
  ((float4*)(x + (size_t)row * 1024))[threadIdx.x] = o;
  ushort4 ob;
  ob.x = f2bf(o.x); ob.y = f2bf(o.y); ob.z = f2bf(o.z); ob.w = f2bf(o.w);
  ((ushort4*)(xbf + (size_t)row * 1024))[threadIdx.x] = ob;
}

// ---------- LayerNorm, 2 rows/block (128 lanes x 8 elems per row) ----------
// MODE 1: f32 in -> f32 out; MODE 2: bf16 in -> bf16 out
template <int MODE>
__global__ __launch_bounds__(256) void ln2_k(const float* __restrict__ Xf,
                                             const u16* __restrict__ Xb,
                                             const float* __restrict__ g,
                                             const float* __restrict__ bta,
                                             u16* __restrict__ obf,
                                             float* __restrict__ of) {
  const int t = threadIdx.x;
  const int row = blockIdx.x * 2 + (t >> 7);
  const int c = t & 127;  // 8 elems per lane
  float v[8];
  if (MODE == 1) {
    float4 a = ((const float4*)(Xf + (size_t)row * 1024))[c * 2];
    float4 b4 = ((const float4*)(Xf + (size_t)row * 1024))[c * 2 + 1];
    v[0] = a.x; v[1] = a.y; v[2] = a.z; v[3] = a.w;
    v[4] = b4.x; v[5] = b4.y; v[6] = b4.z; v[7] = b4.w;
  } else {
    u32x4 p = *(const u32x4*)(Xb + (size_t)row * 1024 + c * 8);
#pragma unroll
    for (int i = 0; i < 4; ++i) {
      v[2 * i] = b2f(p[i]);
      v[2 * i + 1] = b2f(p[i] >> 16);
    }
  }
  float s = 0.f, sq = 0.f;
#pragma unroll
  for (int i = 0; i < 8; ++i) { s += v[i]; sq += v[i] * v[i]; }
#pragma unroll
  for (int o = 1; o < 64; o <<= 1) {
    s += __shfl_xor(s, o);
    sq += __shfl_xor(sq, o);
  }
  __shared__ float red[8];
  const int wid = t >> 6;
  if ((t & 63) == 0) { red[wid * 2] = s; red[wid * 2 + 1] = sq; }
  __syncthreads();
  const int base = (t >> 7) * 4;
  s = red[base] + red[base + 2];
  sq = red[base + 1] + red[base + 3];
  float mean = s * (1.0f / 1024.0f);
  float var = sq * (1.0f / 1024.0f) - mean * mean;
  float rstd = rsqrtf(var + 1e-6f);
  float4 g0 = ((const float4*)g)[c * 2], g1 = ((const float4*)g)[c * 2 + 1];
  float4 b0 = ((const float4*)bta)[c * 2], b1 = ((const float4*)bta)[c * 2 + 1];
  float gv[8] = {g0.x, g0.y, g0.z, g0.w, g1.x, g1.y, g1.z, g1.w};
  float bv[8] = {b0.x, b0.y, b0.z, b0.w, b1.x, b1.y, b1.z, b1.w};
  float y[8];
#pragma unroll
  for (int i = 0; i < 8; ++i) y[i] = (v[i] - mean) * rstd * gv[i] + bv[i];
  if (MODE == 1) {
    float4 o0, o1;
    o0.x = y[0]; o0.y = y[1]; o0.z = y[2]; o0.w = y[3];
    o1.x = y[4]; o1.y = y[5]; o1.z = y[6]; o1.w = y[7];
    ((float4*)(of + (size_t)row * 1024))[c * 2] = o0;
    ((float4*)(of + (size_t)row * 1024))[c * 2 + 1] = o1;
  } else {
    u32x4 o;
#pragma unroll
    for (int i = 0; i < 4; ++i)
      o[i] = (u32)f2bf(y[2 * i]) | ((u32)f2bf(y[2 * i + 1]) << 16);
    *(u32x4*)(obf + (size_t)row * 1024 + c * 8) = o;
  }
}

// ---------- GEMM v2c: 3-buffer counted-vmcnt pipeline + XCD swizzle ----------
template <int BM, int EPI>
__global__ __launch_bounds__(256) void gemm2c(
    const u16* __restrict__ A, const u16* __restrict__ Bt,
    const float* __restrict__ bias, float* __restrict__ X,
    u16* __restrict__ Cbf, int N, int K) {
  constexpr int ABYT = BM * 128;
  constexpr int BBYT = 128 * 128;
  constexpr int BUF = ABYT + BBYT;
  constexpr int MF = BM / 32;
  __shared__ __align__(16) char smem[3 * BUF];

  const int tid = threadIdx.x;
  const int w = tid >> 6, l = tid & 63;
  const int lg = l >> 4, lc = l & 15;
  const int nwg = gridDim.x * gridDim.y;  // divisible by 8 in all uses
  int bid = blockIdx.y * gridDim.x + blockIdx.x;
  bid = (bid & 7) * (nwg >> 3) + (bid >> 3);
  const int m0 = (bid / gridDim.x) * BM, n0 = (bid % gridDim.x) * 128;
  const int wr = w >> 1, wc = w & 1;
  const char* Ab = (const char*)A;
  const char* Bb = (const char*)Bt;
  const size_t sA = (size_t)K * 2;

  f32x4 acc[MF][4];
  const f32x4 zv = {0.f, 0.f, 0.f, 0.f};
#pragma unroll
  for (int m = 0; m < MF; ++m)
#pragma unroll
    for (int n = 0; n < 4; ++n) acc[m][n] = zv;

  const int srow = l >> 3;
  const int scol = ((l & 7) ^ srow) << 4;

  auto stage = [&](char* buf, int kt) {
    const size_t kb = (size_t)kt << 7;
#pragma unroll
    for (int i = 0; i < BM / 32; ++i) {
      const int r = i * 32 + w * 8 + srow;
      gld16(Ab + (size_t)(m0 + r) * sA + kb + scol, buf + (i * 4 + w) * 1024 + l * 16);
    }
#pragma unroll
    for (int i = 0; i < 4; ++i) {
      const int r = i * 32 + w * 8 + srow;
      gld16(Bb + (size_t)(n0 + r) * sA + kb + scol,
            buf + ABYT + (i * 4 + w) * 1024 + l * 16);
    }
  };

  char* p0 = smem;
  char* p1 = smem + BUF;
  char* p2 = smem + 2 * BUF;

  stage(p0, 0);
  stage(p1, 1);
  __builtin_amdgcn_sched_barrier(0);
  asm volatile("s_waitcnt vmcnt(6)" ::: "memory");  // tile 0 resident (6 of 12)
  __builtin_amdgcn_s_barrier();
  __builtin_amdgcn_sched_barrier(0);

  const int nkt = K >> 6;
  for (int kt = 0; kt < nkt; ++kt) {
    if (kt + 2 < nkt) stage(p2, kt + 2);
    const char* As = p0;
    const char* Bs = p0 + ABYT;
    __builtin_amdgcn_s_setprio(1);
#pragma unroll
    for (int ks = 0; ks < 2; ++ks) {
      short8 af[MF], bf4[4];
#pragma unroll
      for (int m = 0; m < MF; ++m) {
        int row = wr * (BM / 2) + m * 16 + lc;
        int col = (ks * 64 + (lg << 4)) ^ ((row & 7) << 4);
        af[m] = *(const short8*)(As + row * 128 + col);
      }
#pragma unroll
      for (int n = 0; n < 4; ++n) {
        int row = wc * 64 + n * 16 + lc;
        int col = (ks * 64 + (lg << 4)) ^ ((row & 7) << 4);
        bf4[n] = *(const short8*)(Bs + row * 128 + col);
      }
#pragma unroll
      for (int m = 0; m < MF; ++m)
#pragma unroll
        for (int n = 0; n < 4; ++n) acc[m][n] = mfma16(af[m], bf4[n], acc[m][n]);
    }
    __builtin_amdgcn_s_setprio(0);
    __builtin_amdgcn_sched_barrier(0);
    if (kt + 2 < nkt) {
      asm volatile("s_waitcnt vmcnt(6) lgkmcnt(0)" ::: "memory");
    } else {
      asm volatile("s_waitcnt vmcnt(0) lgkmcnt(0)" ::: "memory");
    }
    __builtin_amdgcn_s_barrier();
    __builtin_amdgcn_sched_barrier(0);
    char* t = p0; p0 = p1; p1 = p2; p2 = t;
  }

  float bv[4];
#pragma unroll
  for (int n = 0; n < 4; ++n) bv[n] = bias[n0 + wc * 64 + n * 16 + lc];

  if (EPI <= 1) {
    u16* ct = (u16*)smem;
#pragma unroll
    for (int m = 0; m < MF; ++m)
#pragma unroll
      for (int n = 0; n < 4; ++n)
#pragma unroll
        for (int r = 0; r < 4; ++r) {
          int row = wr * (BM / 2) + m * 16 + (lg << 2) + r;
          int col = wc * 64 + n * 16 + lc;
          float v = acc[m][n][r] + bv[n];
          if (EPI == 1) v = v > 0.f ? v : 0.f;
          ct[row * 136 + col] = f2bf(v);
        }
    __syncthreads();
#pragma unroll
    for (int j = 0; j < BM / 16; ++j) {
      int c = j * 256 + tid;
      int row = c >> 4, colb = (c & 15) * 8;
      *(short8*)(Cbf + (size_t)(m0 + row) * N + n0 + colb) =
          *(const short8*)(ct + row * 136 + colb);
    }
  } else if (EPI == 2) {
    float* cf = (float*)smem;
#pragma unroll
    for (int m = 0; m < MF; ++m)
#pragma unroll
      for (int n = 0; n < 4; ++n)
#pragma unroll
        for (int r = 0; r < 4; ++r) {
          int row = wr * (BM / 2) + m * 16 + (lg << 2) + r;
          int col = wc * 64 + n * 16 + lc;
          cf[row * 128 + col] = acc[m][n][r] + bv[n];
        }
    __syncthreads();
#pragma unroll
    for (int j = 0; j < BM / 8; ++j) {
      int c = j * 256 + tid;
      int row = c >> 5, colb = (c & 31) * 4;
      size_t idx = (size_t)(m0 + row) * N + n0 + colb;
      float4 s4 = *(const float4*)(cf + row * 128 + colb);
      float4 xv = *(const float4*)(X + idx);
      xv.x += s4.x; xv.y += s4.y; xv.z += s4.z; xv.w += s4.w;
      *(float4*)(X + idx) = xv;
      ushort4 ob;
      ob.x = f2bf(xv.x); ob.y = f2bf(xv.y); ob.z = f2bf(xv.z); ob.w = f2bf(xv.w);
      *(ushort4*)(Cbf + idx) = ob;
    }
  } else {  // EPI == 3: V transposed per head
    u16* ct = (u16*)smem;
#pragma unroll
    for (int m = 0; m < MF; ++m)
#pragma unroll
      for (int n = 0; n < 4; ++n)
#pragma unroll
        for (int r = 0; r < 4; ++r) {
          int row = wr * (BM / 2) + m * 16 + (lg << 2) + r;
          int col = wc * 64 + n * 16 + lc;
          ct[col * 136 + row] = f2bf(acc[m][n][r] + bv[n]);
        }
    __syncthreads();
    const int bb = m0 >> 10, ms = m0 & 1023;
#pragma unroll
    for (int j = 0; j < BM / 16; ++j) {
      int flat = j * 256 + tid;
      int sb = flat & (BM / 8 - 1);
      int col = flat / (BM / 8);
      int n = n0 + col;
      u16* dst = Cbf + (size_t)(((bb << 4) + (n >> 6)) * 64 + (n & 63)) * 1024 + ms + sb * 8;
      *(short8*)dst = *(const short8*)(ct + col * 136 + sb * 8);
    }
  }
}

// ---------- GEMM v3b: 256x256 tile, 8 waves, per-wave 128x64. EPI 1: relu->bf16 ----------
template <int EPI>
__global__ __launch_bounds__(512) void gemm3b(
    const u16* __restrict__ A, const u16* __restrict__ Bt,
    const float* __restrict__ bias, u16* __restrict__ Cbf, int N, int K) {
  constexpr int ABYT = 32768;  // 256 rows x 64k x 2B
  constexpr int BBYT = 32768;
  __shared__ __align__(16) char smem[2 * (ABYT + BBYT)];  // 128KB

  const int tid = threadIdx.x;
  const int w = tid >> 6, l = tid & 63;
  const int lg = l >> 4, lc = l & 15;
  const int nwg = gridDim.x * gridDim.y;  // divisible by 8
  int bid = blockIdx.y * gridDim.x + blockIdx.x;
  bid = (bid & 7) * (nwg >> 3) + (bid >> 3);
  const int m0 = (bid / gridDim.x) * 256, n0 = (bid % gridDim.x) * 256;
  const int wr = w >> 2, wc = w & 3;  // 2 m-waves x 4 n-waves
  const char* Ab = (const char*)A;
  const char* Bb = (const char*)Bt;
  const size_t sA = (size_t)K * 2;

  f32x4 acc[8][4];
  const f32x4 zv = {0.f, 0.f, 0.f, 0.f};
#pragma unroll
  for (int m = 0; m < 8; ++m)
#pragma unroll
    for (int n = 0; n < 4; ++n) acc[m][n] = zv;

  const int srow = l >> 3;
  const int scol = ((l & 7) ^ srow) << 4;

  auto stage = [&](char* buf, int kt) {
    const size_t kb = (size_t)kt << 7;
#pragma unroll
    for (int i = 0; i < 4; ++i) {
      const int r = i * 64 + w * 8 + srow;
      gld16(Ab + (size_t)(m0 + r) * sA + kb + scol, buf + (i * 8 + w) * 1024 + l * 16);
    }
#pragma unroll
    for (int i = 0; i < 4; ++i) {
      const int r = i * 64 + w * 8 + srow;
      gld16(Bb + (size_t)(n0 + r) * sA + kb + scol,
            buf + ABYT + (i * 8 + w) * 1024 + l * 16);
    }
  };

  stage(smem, 0);
  __syncthreads();

  const int nkt = K >> 6;
  int cur = 0;
  for (int kt = 0; kt < nkt; ++kt) {
    char* As = smem + cur * (ABYT + BBYT);
    char* Bs = As + ABYT;
    if (kt + 1 < nkt) stage(smem + (cur ^ 1) * (ABYT + BBYT), kt + 1);
    __builtin_amdgcn_s_setprio(1);
#pragma unroll
    for (int ks = 0; ks < 2; ++ks) {
      short8 bf4[4];
#pragma unroll
      for (int n = 0; n < 4; ++n) {
        int row = wc * 64 + n * 16 + lc;
        int col = (ks * 64 + (lg << 4)) ^ ((row & 7) << 4);
        bf4[n] = *(const short8*)(Bs + row * 128 + col);
      }
#pragma unroll
      for (int m = 0; m < 8; ++m) {
        int row = wr * 128 + m * 16 + lc;
        int col = (ks * 64 + (lg << 4)) ^ ((row & 7) << 4);
        short8 af = *(const short8*)(As + row * 128 + col);
#pragma unroll
        for (int n = 0; n < 4; ++n) acc[m][n] = mfma16(af, bf4[n], acc[m][n]);
      }
    }
    __builtin_amdgcn_s_setprio(0);
    __syncthreads();
    cur ^= 1;
  }

  // ---- epilogue: two half-tile LDS passes ([128][264] u16), coalesced stores ----
  float bv[4];
#pragma unroll
  for (int n = 0; n < 4; ++n) bv[n] = bias[n0 + wc * 64 + n * 16 + lc];
  u16* ct = (u16*)smem;
#pragma unroll
  for (int h = 0; h < 2; ++h) {
    __syncthreads();
    if (wr == h) {
#pragma unroll
      for (int m = 0; m < 8; ++m)
#pragma unroll
        for (int n = 0; n < 4; ++n)
#pragma unroll
          for (int r = 0; r < 4; ++r) {
            int row = m * 16 + (lg << 2) + r;  // 0..127 within half
            int col = wc * 64 + n * 16 + lc;
            float v = acc[m][n][r] + bv[n];
            if (EPI == 1) v = v > 0.f ? v : 0.f;
            ct[row * 264 + col] = f2bf(v);
          }
    }
    __syncthreads();
#pragma unroll
    for (int j = 0; j < 8; ++j) {  // 128 rows x 32 col-blocks = 4096 / 512 threads
      int c = j * 512 + tid;
      int row = c >> 5, colb = (c & 31) * 8;
      *(short8*)(Cbf + (size_t)(m0 + h * 128 + row) * N + n0 + colb) =
          *(const short8*)(ct + row * 264 + colb);
    }
  }
}

// ---------- GEMM v3q: 256x256 tile over N=3072 (QKV fused) ----------
__global__ __launch_bounds__(512) void gemm3q(
    const u16* __restrict__ A, const u16* __restrict__ Bt,
    const float* __restrict__ bias, u16* __restrict__ Cqk, u16* __restrict__ Vt, int K) {
  constexpr int ABYT = 32768;
  constexpr int BBYT = 32768;
  __shared__ __align__(16) char smem[2 * (ABYT + BBYT)];  // 128KB

  const int tid = threadIdx.x;
  const int w = tid >> 6, l = tid & 63;
  const int lg = l >> 4, lc = l & 15;
  const int nwg = gridDim.x * gridDim.y;  // 12*16 = 192, divisible by 8
  int bid = blockIdx.y * gridDim.x + blockIdx.x;
  bid = (bid & 7) * (nwg >> 3) + (bid >> 3);
  const int m0 = (bid / gridDim.x) * 256, n0 = (bid % gridDim.x) * 256;
  const int wr = w >> 2, wc = w & 3;
  const char* Ab = (const char*)A;
  const char* Bb = (const char*)Bt;
  const size_t sA = (size_t)K * 2;

  f32x4 acc[8][4];
  const f32x4 zv = {0.f, 0.f, 0.f, 0.f};
#pragma unroll
  for (int m = 0; m < 8; ++m)
#pragma unroll
    for (int n = 0; n < 4; ++n) acc[m][n] = zv;

  const int srow = l >> 3;
  const int scol = ((l & 7) ^ srow) << 4;

  auto stage = [&](char* buf, int kt) {
    const size_t kb = (size_t)kt << 7;
#pragma unroll
    for (int i = 0; i < 4; ++i) {
      const int r = i * 64 + w * 8 + srow;
      gld16(Ab + (size_t)(m0 + r) * sA + kb + scol, buf + (i * 8 + w) * 1024 + l * 16);
    }
#pragma unroll
    for (int i = 0; i < 4; ++i) {
      const int r = i * 64 + w * 8 + srow;
      gld16(Bb + (size_t)(n0 + r) * sA + kb + scol,
            buf + ABYT + (i * 8 + w) * 1024 + l * 16);
    }
  };

  stage(smem, 0);
  __syncthreads();

  const int nkt = K >> 6;
  int cur = 0;
  for (int kt = 0; kt < nkt; ++kt) {
    char* As = smem + cur * (ABYT + BBYT);
    char* Bs = As + ABYT;
    if (kt + 1 < nkt) stage(smem + (cur ^ 1) * (ABYT + BBYT), kt + 1);
    __builtin_amdgcn_s_setprio(1);
#pragma unroll
    for (int ks = 0; ks < 2; ++ks) {
      short8 bf4[4];
#pragma unroll
      for (int n = 0; n < 4; ++n) {
        int row = wc * 64 + n * 16 + lc;
        int col = (ks * 64 + (lg << 4)) ^ ((row & 7) << 4);
        bf4[n] = *(const short8*)(Bs + row * 128 + col);
      }
#pragma unroll
      for (int m = 0; m < 8; ++m) {
        int row = wr * 128 + m * 16 + lc;
        int col = (ks * 64 + (lg << 4)) ^ ((row & 7) << 4);
        short8 af = *(const short8*)(As + row * 128 + col);
#pragma unroll
        for (int n = 0; n < 4; ++n) acc[m][n] = mfma16(af, bf4[n], acc[m][n]);
      }
    }
    __builtin_amdgcn_s_setprio(0);
    __syncthreads();
    cur ^= 1;
  }

  float bv[4];
#pragma unroll
  for (int n = 0; n < 4; ++n) bv[n] = bias[n0 + wc * 64 + n * 16 + lc];
  u16* ct = (u16*)smem;

  if (n0 < 2048) {
    // Q/K region: standard bf16 store, row stride 2048
#pragma unroll
    for (int h = 0; h < 2; ++h) {
      __syncthreads();
      if (wr == h) {
#pragma unroll
        for (int m = 0; m < 8; ++m)
#pragma unroll
          for (int n = 0; n < 4; ++n)
#pragma unroll
            for (int r = 0; r < 4; ++r) {
              int row = m * 16 + (lg << 2) + r;
              int col = wc * 64 + n * 16 + lc;
              ct[row * 264 + col] = f2bf(acc[m][n][r] + bv[n]);
            }
      }
      __syncthreads();
#pragma unroll
      for (int j = 0; j < 8; ++j) {
        int c = j * 512 + tid;
        int row = c >> 5, colb = (c & 31) * 8;
        *(short8*)(Cqk + (size_t)(m0 + h * 128 + row) * 2048 + n0 + colb) =
            *(const short8*)(ct + row * 264 + colb);
      }
    }
  } else {
    // V region: per-head transpose Vt[(b*16+h)*64+d][s]
    const int bb = m0 >> 10, ms = m0 & 1023;
#pragma unroll
    for (int h = 0; h < 2; ++h) {
      __syncthreads();
      if (wr == h) {
#pragma unroll
        for (int m = 0; m < 8; ++m)
#pragma unroll
          for (int n = 0; n < 4; ++n)
#pragma unroll
            for (int r = 0; r < 4; ++r) {
              int row = m * 16 + (lg << 2) + r;  // s-offset within half, 0..127
              int col = wc * 64 + n * 16 + lc;   // 0..255
              ct[col * 136 + row] = f2bf(acc[m][n][r] + bv[n]);
            }
      }
      __syncthreads();
#pragma unroll
      for (int j = 0; j < 8; ++j) {  // 256 cols x 16 row-chunks = 4096 / 512
        int flat = j * 512 + tid;
        int col = flat >> 4, sb = flat & 15;
        int n = n0 + col - 2048;  // V col in [0,1024)
        u16* dst = Vt + (size_t)(((bb << 4) + (n >> 6)) * 64 + (n & 63)) * 1024 +
                   ms + h * 128 + sb * 8;
        *(short8*)dst = *(const short8*)(ct + col * 136 + sb * 8);
      }
    }
  }
}

// ---------- flash attention v6: 4 waves/block, 2 q-tiles per wave (K/V frag sharing) ----------
// Causal: wave w of block p handles qA = p*4+w (low) and qB = 31-qA (high) -> perfectly
// balanced blocks; cross: qA = p*4+w, qB = 16+qA. K/V LDS frag reads serve BOTH q-sets'
// MFMAs when both active -> halves the dominant LDS traffic. blk_nst = 8-p (causal)/8.
template <bool CAUSAL>
__global__ __launch_bounds__(256, 2) void attn_q2(
    const u16* __restrict__ Qp, int sQ, const u16* __restrict__ Kp, int sK,
    const u16* __restrict__ Vt, const int* __restrict__ tgt,
    u16* __restrict__ Out) {
  __shared__ __align__(16) char smem[2][32768];
  const int tid = threadIdx.x;
  const int w = tid >> 6, l = tid & 63;
  const int bh = blockIdx.x & 63;
  const int p = blockIdx.x >> 6;  // in [0,4)
  const int b = bh >> 4, h = bh & 15;
  const int lq = l & 31, hi = l >> 5;

  const int qA = p * 4 + w;                       // [0,16)
  const int qB = CAUSAL ? (31 - qA) : (16 + qA);  // [16,32)
  const int q0A = qA * 32, q0B = qB * 32;

  const char* Kc = (const char*)(Kp + (size_t)b * 1024 * sK + h * 64);
  const char* Vc = (const char*)(Vt + (size_t)bh * 64 * 1024);
  const u16* Qh = Qp + (size_t)b * 1024 * sQ + h * 64;

  short8 qbA[4], qbB[4];
  {
    const u16* qrA = Qh + (size_t)(q0A + lq) * sQ + hi * 8;
    const u16* qrB = Qh + (size_t)(q0B + lq) * sQ + hi * 8;
#pragma unroll
    for (int c = 0; c < 4; ++c) {
      qbA[c] = *(const short8*)(qrA + c * 16);
      qbB[c] = *(const short8*)(qrB + c * 16);
    }
  }

  bool rokA = true, rokB = true;
  int nktA = 16, nktB = 16;
  int blk_nst = CAUSAL ? (8 - p) : 8;  // super-tiles (128 keys)
  if (CAUSAL) {
    rokA = (tgt[b * 1024 + q0A + lq] != 1);
    rokB = (tgt[b * 1024 + q0B + lq] != 1);
    bool anypad_w = __any(!rokA || !rokB);
    __shared__ int s_pad;
    if (tid == 0) s_pad = 0;
    __syncthreads();
    if (anypad_w && l == 0) s_pad = 1;
    __syncthreads();
    // pad row => all keys masked => uniform softmax over all 1024 keys
    if (s_pad) { nktA = 16; nktB = 16; blk_nst = 8; }
    else { nktA = (qA >> 1) + 1; nktB = (qB >> 1) + 1; }
  }

  const int srow = l >> 3;
  const int scol = ((l & 7) ^ srow) << 4;
  auto stage = [&](int buf, int st) {
    const int k0 = st * 128;
    char* Ks = smem[buf];
    char* Vs = smem[buf] + 16384;
#pragma unroll
    for (int g = 0; g < 2; ++g) {
      const int r = w * 16 + g * 8 + srow;  // 4 waves cover rows 0..63
#pragma unroll
      for (int t2 = 0; t2 < 2; ++t2) {
        gld16(Kc + (size_t)(k0 + t2 * 64 + r) * sK * 2 + scol, Ks + t2 * 8192 + r * 128);
        gld16(Vc + (size_t)r * 2048 + (size_t)(k0 + t2 * 64) * 2 + scol,
              Vs + t2 * 8192 + r * 128);
      }
    }
  };

  float mA = -3.0e38f, lsA = 0.f, mB = -3.0e38f, lsB = 0.f;
  f32x16 oaccA[2], oaccB[2];
#pragma unroll
  for (int r = 0; r < 16; ++r) {
    oaccA[0][r] = 0.f; oaccA[1][r] = 0.f;
    oaccB[0][r] = 0.f; oaccB[1][r] = 0.f;
  }

  // per-set softmax+pack (masking, tile-max, defer-rescale, exp/sum, bf16 A-frags)
  auto dotile = [&](f32x16 (&stt)[2], float& m_, float& ls_, f32x16 (&oacc_)[2],
                    short8 (&pa_)[4], int q0_, bool rok_, int k0) {
    if (CAUSAL) {
#pragma unroll
      for (int s = 0; s < 2; ++s) {
        if (!rok_ || (k0 + s * 32 + 31 > q0_)) {
#pragma unroll
          for (int r = 0; r < 16; ++r) {
            int kg = k0 + s * 32 + (r & 3) + 8 * (r >> 2) + 4 * hi;
            bool ok = rok_ && (kg <= q0_ + lq);
            if (!ok) stt[s][r] = -1e9f;
          }
        }
      }
    }
    float tm;
    {
      float v[16];
#pragma unroll
      for (int r = 0; r < 16; ++r) v[r] = fmaxf(stt[0][r], stt[1][r]);
#pragma unroll
      for (int w2 = 8; w2 >= 1; w2 >>= 1)
#pragma unroll
        for (int r = 0; r < w2; ++r) v[r] = fmaxf(v[r], v[r + w2]);
      tm = v[0];
    }
    tm = fmaxf(tm, __shfl_xor(tm, 32));
    if (!__all(tm <= m_ + 8.0f)) {
      float mn = fmaxf(m_, tm);
      float alpha = __expf(m_ - mn);
      ls_ *= alpha;
      m_ = mn;
#pragma unroll
      for (int r = 0; r < 16; ++r) {
        int crow = (r & 3) + 8 * (r >> 2) + 4 * hi;
        float av = __shfl(alpha, crow);
        oacc_[0][r] *= av;
        oacc_[1][r] *= av;
      }
    }
    float t0 = 0.f, t1 = 0.f, t2s = 0.f, t3 = 0.f;
#pragma unroll
    for (int s = 0; s < 2; ++s) {
#pragma unroll
      for (int r = 0; r < 16; ++r) {
        float e = __expf(stt[s][r] - m_);
        stt[s][r] = e;
        if ((r & 3) == 0) t0 += e;
        else if ((r & 3) == 1) t1 += e;
        else if ((r & 3) == 2) t2s += e;
        else t3 += e;
      }
    }
    float ts = (t0 + t1) + (t2s + t3);
    ts += __shfl_xor(ts, 32);
    ls_ += ts;
    // pack P -> bf16 A-frags
#pragma unroll
    for (int s = 0; s < 2; ++s) {
      u32 cc[8];
#pragma unroll
      for (int t = 0; t < 4; ++t) {
        cc[2 * t]     = cvtpk(stt[s][4 * t + 0], stt[s][4 * t + 1]);
        cc[2 * t + 1] = cvtpk(stt[s][4 * t + 2], stt[s][4 * t + 3]);
      }
      plswap(cc[0], cc[2]);
      plswap(cc[1], cc[3]);
      plswap(cc[4], cc[6]);
      plswap(cc[5], cc[7]);
      u32x4 w0 = {cc[0], cc[1], cc[2], cc[3]};
      u32x4 w1 = {cc[4], cc[5], cc[6], cc[7]};
      pa_[2 * s]     = __builtin_bit_cast(short8, w0);
      pa_[2 * s + 1] = __builtin_bit_cast(short8, w1);
    }
  };

  stage(0, 0);
  __syncthreads();
  int cur = 0;

  for (int st = 0; st < blk_nst; ++st) {
    if (st + 1 < blk_nst) stage(cur ^ 1, st + 1);
#pragma unroll
    for (int t2 = 0; t2 < 2; ++t2) {
      const int t64 = st * 2 + t2;
      const bool actA = t64 < nktA;
      const bool actB = t64 < nktB;
      if (actA || actB) {
        const char* Ks = smem[cur] + t2 * 8192;
        const char* Vs = smem[cur] + 16384 + t2 * 8192;
        const int k0 = t64 * 64;
        // ---- QK^T: shared K-frag reads ----
        f32x16 sA2[2], sB2[2];
        __builtin_amdgcn_s_setprio(1);
#pragma unroll
        for (int s = 0; s < 2; ++s) {
          const int row = s * 32 + lq;
          const int swz = (row & 7) << 4;
          f32x16 a0, a1;
#pragma unroll
          for (int r = 0; r < 16; ++r) { a0[r] = 0.f; a1[r] = 0.f; }
#pragma unroll
          for (int c = 0; c < 4; ++c) {
            short8 kb = *(const short8*)(Ks + row * 128 + ((c * 32 + hi * 16) ^ swz));
            if (actA) a0 = mfma32(kb, qbA[c], a0);
            if (actB) a1 = mfma32(kb, qbB[c], a1);
          }
          sA2[s] = a0;
          sB2[s] = a1;
        }
        __builtin_amdgcn_s_setprio(0);
        // ---- softmax per set ----
        short8 paA[4], paB[4];
        if (actA) dotile(sA2, mA, lsA, oaccA, paA, q0A, rokA, k0);
        if (actB) dotile(sB2, mB, lsB, oaccB, paB, q0B, rokB, k0);
        // ---- PV: shared V-frag reads ----
        __builtin_amdgcn_s_setprio(1);
#pragma unroll
        for (int dt = 0; dt < 2; ++dt) {
          const int row = dt * 32 + lq;
          const int swz = (row & 7) << 4;
#pragma unroll
          for (int c = 0; c < 4; ++c) {
            short8 vb = *(const short8*)(Vs + row * 128 + ((c * 32 + hi * 16) ^ swz));
            if (actA) oaccA[dt] = mfma32(paA[c], vb, oaccA[dt]);
            if (actB) oaccB[dt] = mfma32(paB[c], vb, oaccB[dt]);
          }
        }
        __builtin_amdgcn_s_setprio(0);
      }
    }
    __syncthreads();
    cur ^= 1;
  }

  // ---- finalize both sets ----
#pragma unroll
  for (int r = 0; r < 16; ++r) {
    int crow = (r & 3) + 8 * (r >> 2) + 4 * hi;
    float lvA = __shfl(lsA, crow);
    float lvB = __shfl(lsB, crow);
    float liA = 1.0f / lvA;
    float liB = 1.0f / lvB;
    size_t baseA = ((size_t)b * 1024 + q0A + crow) * 1024 + h * 64 + lq;
    size_t baseB = ((size_t)b * 1024 + q0B + crow) * 1024 + h * 64 + lq;
    Out[baseA] = f2bf(oaccA[0][r] * liA);
    Out[baseA + 32] = f2bf(oaccA[1][r] * liA);
    Out[baseB] = f2bf(oaccB[0][r] * liB);
    Out[baseB + 32] = f2bf(oaccB[1][r] * liB);
  }
}

// =====================================================================
extern "C" void kernel_launch(void* const* d_in, const int* in_sizes, int n_in,
                              void* d_out, int out_size, void* d_ws, size_t ws_size,
                              hipStream_t stream) {
  const int* tgt = (const int*)d_in[0];
  const float* memory = (const float*)d_in[1];
  const float* emb = (const float*)d_in[2];
  const float* ff_w1 = (const float*)d_in[3];
  const float* ff_b1 = (const float*)d_in[4];
  const float* ff_w2 = (const float*)d_in[5];
  const float* ff_b2 = (const float*)d_in[6];
  const float* ln_g = (const float*)d_in[7];
  const float* ln_b = (const float*)d_in[8];
  const float* sa_wq = (const float*)d_in[9];
  const float* sa_bq = (const float*)d_in[10];
  const float* sa_wk = (const float*)d_in[11];
  const float* sa_bk = (const float*)d_in[12];
  const float* sa_wv = (const float*)d_in[13];
  const float* sa_bv = (const float*)d_in[14];
  const float* sa_wo = (const float*)d_in[15];
  const float* sa_bo = (const float*)d_in[16];
  const float* xa_wq = (const float*)d_in[17];
  const float* xa_bq = (const float*)d_in[18];
  const float* xa_wk = (const float*)d_in[19];
  const float* xa_bk = (const float*)d_in[20];
  const float* xa_wv = (const float*)d_in[21];
  const float* xa_bv = (const float*)d_in[22];
  const float* xa_wo = (const float*)d_in[23];
  const float* xa_bo = (const float*)d_in[24];

  char* ws = (char*)d_ws;
  size_t off = 0;
  auto alloc = [&](size_t bytes) {
    char* p = ws + off;
    off += (bytes + 255) & ~(size_t)255;
    return p;
  };
  float* x   = (float*)alloc(4096ull * 1024 * 4);
  u16* xbf   = (u16*)alloc(4096ull * 1024 * 2);
  u16* nbf   = (u16*)alloc(4096ull * 1024 * 2);
  u16* qkv   = (u16*)alloc(4096ull * 2048 * 2);
  u16* q2    = (u16*)alloc(4096ull * 1024 * 2);
  u16* attn  = (u16*)alloc(4096ull * 1024 * 2);
  u16* vt    = (u16*)alloc(64ull * 64 * 1024 * 2);
  u16* kx    = (u16*)alloc(4096ull * 1024 * 2);
  u16* vtx   = (u16*)alloc(64ull * 64 * 1024 * 2);
  u16* h1    = (u16*)alloc(4096ull * 4096 * 2);
  u16* memb  = (u16*)alloc(4096ull * 1024 * 2);
  u16* w_qkv = (u16*)alloc(3072ull * 1024 * 2);
  u16* w_sao = (u16*)alloc(1024ull * 1024 * 2);
  u16* w_xaq = (u16*)alloc(1024ull * 1024 * 2);
  u16* w_xak = (u16*)alloc(1024ull * 1024 * 2);
  u16* w_xav = (u16*)alloc(1024ull * 1024 * 2);
  u16* w_xao = (u16*)alloc(1024ull * 1024 * 2);
  u16* w_ff1 = (u16*)alloc(4096ull * 1024 * 2);
  u16* w_ff2 = (u16*)alloc(1024ull * 4096 * 2);
  float* b_qkv = (float*)alloc(3072 * 4);
  float* b_xaq = (float*)alloc(1024 * 4);
  float* pe    = (float*)alloc(1024ull * 1024 * 4);

  dim3 blk(256);
  dim3 b32(32, 8);
  const float QS = 0.125f;  // 1/sqrt(dk), folded into wq/bq

  // ---- setup: batched weight conversion/transpose (shared across the 4 stacks) ----
  W8 wp;
  wp.src[0] = sa_wq; wp.dst[0] = w_qkv;               wp.scale[0] = QS;
  wp.src[1] = sa_wk; wp.dst[1] = w_qkv + 1024 * 1024; wp.scale[1] = 1.f;
  wp.src[2] = sa_wv; wp.dst[2] = w_qkv + 2048 * 1024; wp.scale[2] = 1.f;
  wp.src[3] = sa_wo; wp.dst[3] = w_sao;               wp.scale[3] = 1.f;
  wp.src[4] = xa_wq; wp.dst[4] = w_xaq;               wp.scale[4] = QS;
  wp.src[5] = xa_wk; wp.dst[5] = w_xak;               wp.scale[5] = 1.f;
  wp.src[6] = xa_wv; wp.dst[6] = w_xav;               wp.scale[6] = 1.f;
  wp.src[7] = xa_wo; wp.dst[7] = w_xao;               wp.scale[7] = 1.f;
  transpose_wt8<<<dim3(32, 32, 8), b32, 0, stream>>>(wp);
  transpose_wt<<<dim3(128, 32), b32, 0, stream>>>(ff_w1, w_ff1, 1024, 4096, 1.f);
  transpose_wt<<<dim3(32, 128), b32, 0, stream>>>(ff_w2, w_ff2, 4096, 1024, 1.f);
  prep_bias<<<16, blk, 0, stream>>>(sa_bq, sa_bk, sa_bv, xa_bq, b_qkv, b_xaq, QS);
  cvt_bf16<<<4096, blk, 0, stream>>>(memory, memb);
  pe_k<<<1024, blk, 0, stream>>>(pe);
  embed_pe<<<4096, blk, 0, stream>>>(tgt, emb, pe, x, xbf);

  // ---- hoisted cross-attention K/V (identical in all 4 stacks) ----
  gemm2c<64, 0><<<dim3(8, 64), blk, 0, stream>>>(memb, w_xak, xa_bk, nullptr, kx, 1024, 1024);
  gemm2c<64, 3><<<dim3(8, 64), blk, 0, stream>>>(memb, w_xav, xa_bv, nullptr, vtx, 1024, 1024);

  for (int layer = 0; layer < 4; ++layer) {
    // self-attention block (fused QKV + V-transpose)
    ln2_k<2><<<2048, blk, 0, stream>>>(nullptr, xbf, ln_g, ln_b, nbf, nullptr);
    gemm3q<<<dim3(12, 16), dim3(512), 0, stream>>>(nbf, w_qkv, b_qkv, qkv, vt, 1024);
    attn_q2<true><<<256, blk, 0, stream>>>(qkv, 2048, qkv + 1024, 2048, vt, tgt, attn);
    gemm2c<64, 2><<<dim3(8, 64), blk, 0, stream>>>(attn, w_sao, sa_bo, x, xbf, 1024, 1024);
    // cross-attention block
    ln2_k<2><<<2048, blk, 0, stream>>>(nullptr, xbf, ln_g, ln_b, nbf, nullptr);
    gemm2c<64, 0><<<dim3(8, 64), blk, 0, stream>>>(nbf, w_xaq, b_xaq, nullptr, q2, 1024, 1024);
    attn_q2<false><<<256, blk, 0, stream>>>(q2, 1024, kx, 1024, vtx, nullptr, attn);
    gemm2c<64, 2><<<dim3(8, 64), blk, 0, stream>>>(attn, w_xao, xa_bo, x, xbf, 1024, 1024);
    // FFN block
    ln2_k<2><<<2048, blk, 0, stream>>>(nullptr, xbf, ln_g, ln_b, nbf, nullptr);
    gemm3b<1><<<dim3(16, 16), dim3(512), 0, stream>>>(nbf, w_ff1, ff_b1, h1, 4096, 1024);
    gemm2c<64, 2><<<dim3(8, 64), blk, 0, stream>>>(h1, w_ff2, ff_b2, x, xbf, 1024, 4096);
  }
  ln2_k<1><<<2048, blk, 0, stream>>>(x, nullptr, ln_g, ln_b, nullptr, (float*)d_out);
}

// Round 21
// 1037.642 us; speedup vs baseline: 1.1673x; 1.1673x over previous
//
#include <hip/hip_runtime.h>

typedef unsigned short u16;
typedef unsigned int u32;
typedef float f32x4 __attribute__((ext_vector_type(4)));
typedef float f32x16 __attribute__((ext_vector_type(16)));
typedef __bf16 bf16x8 __attribute__((ext_vector_type(8)));
typedef short short8 __attribute__((ext_vector_type(8)));
typedef u32 u32x4 __attribute__((ext_vector_type(4)));

#define DINLINE static __device__ __forceinline__

// ---------- helpers ----------
DINLINE u16 f2bf(float f) {  // RNE float->bf16
  u32 u = __builtin_bit_cast(u32, f);
  u += 0x7fffu + ((u >> 16) & 1u);
  return (u16)(u >> 16);
}

DINLINE float b2f(u32 lo16) {  // low 16 bits = bf16
  u32 u = lo16 << 16;
  return __builtin_bit_cast(float, u);
}

DINLINE f32x4 mfma16(short8 a, short8 b, f32x4 c) {
  return __builtin_amdgcn_mfma_f32_16x16x32_bf16(
      __builtin_bit_cast(bf16x8, a), __builtin_bit_cast(bf16x8, b), c, 0, 0, 0);
}

DINLINE f32x16 mfma32(short8 a, short8 b, f32x16 c) {
  return __builtin_amdgcn_mfma_f32_32x32x16_bf16(
      __builtin_bit_cast(bf16x8, a), __builtin_bit_cast(bf16x8, b), c, 0, 0, 0);
}

DINLINE u32 cvtpk(float lo, float hi) {
  u32 r;
  asm("v_cvt_pk_bf16_f32 %0, %1, %2" : "=v"(r) : "v"(lo), "v"(hi));
  return r;
}

DINLINE void plswap(u32& a, u32& b) {
  auto r = __builtin_amdgcn_permlane32_swap(a, b, false, false);
  a = (u32)r[0];
  b = (u32)r[1];
}

DINLINE void gld16(const void* g, void* l) {
  __builtin_amdgcn_global_load_lds(
      (const __attribute__((address_space(1))) void*)g,
      (__attribute__((address_space(3))) void*)l, 16, 0, 0);
}

// ---------- batched 1024x1024 weight transpose (8 matrices in one dispatch) ----------
struct W8 {
  const float* src[8];
  u16* dst[8];
  float scale[8];
};
__global__ __launch_bounds__(256) void transpose_wt8(W8 p) {
  __shared__ float tile[32][33];
  const int z = blockIdx.z;
  const float* __restrict__ src = p.src[z];
  u16* __restrict__ dst = p.dst[z];
  const float scale = p.scale[z];
  int n0 = blockIdx.x * 32, k0 = blockIdx.y * 32;
  int tx = threadIdx.x, ty = threadIdx.y;  // 32 x 8
#pragma unroll
  for (int j = 0; j < 32; j += 8)
    tile[ty + j][tx] = src[(size_t)(k0 + ty + j) * 1024 + n0 + tx];
  __syncthreads();
#pragma unroll
  for (int j = 0; j < 32; j += 8)
    dst[(size_t)(n0 + ty + j) * 1024 + k0 + tx] = f2bf(tile[tx][ty + j] * scale);
}

// ---------- weight transpose+convert: src fp32 [K][N] -> dst bf16 [N][K] (x scale) ----------
__global__ __launch_bounds__(256) void transpose_wt(const float* __restrict__ src,
                                                    u16* __restrict__ dst, int K, int N,
                                                    float scale) {
  __shared__ float tile[32][33];
  int n0 = blockIdx.x * 32, k0 = blockIdx.y * 32;
  int tx = threadIdx.x, ty = threadIdx.y;  // 32 x 8
#pragma unroll
  for (int j = 0; j < 32; j += 8)
    tile[ty + j][tx] = src[(size_t)(k0 + ty + j) * N + n0 + tx];
  __syncthreads();
#pragma unroll
  for (int j = 0; j < 32; j += 8)
    dst[(size_t)(n0 + ty + j) * K + k0 + tx] = f2bf(tile[tx][ty + j] * scale);
}

// ---------- fp32 -> bf16 elementwise (4/thread) ----------
__global__ __launch_bounds__(256) void cvt_bf16(const float* __restrict__ src,
                                                u16* __restrict__ dst) {
  size_t i = (size_t)blockIdx.x * 256 + threadIdx.x;
  float4 v = ((const float4*)src)[i];
  u32 lo = (u32)f2bf(v.x) | ((u32)f2bf(v.y) << 16);
  u32 hi = (u32)f2bf(v.z) | ((u32)f2bf(v.w) << 16);
  uint2 o; o.x = lo; o.y = hi;
  ((uint2*)dst)[i] = o;
}

// ---------- bias prep: b_qkv[3072] (q scaled) and b_xaq[1024] in one dispatch ----------
__global__ void prep_bias(const float* __restrict__ a, const float* __restrict__ b,
                          const float* __restrict__ c, const float* __restrict__ xq,
                          float* __restrict__ oqkv, float* __restrict__ oxq, float sa) {
  int i = blockIdx.x * 256 + threadIdx.x;  // 4096 total
  if (i < 1024) oqkv[i] = a[i] * sa;
  else if (i < 2048) oqkv[i] = b[i - 1024];
  else if (i < 3072) oqkv[i] = c[i - 2048];
  else oxq[i - 3072] = xq[i - 3072] * sa;
}

// ---------- positional-encoding table pe[s][c], s<1024 ----------
__global__ __launch_bounds__(256) void pe_k(float* __restrict__ pe) {
  int s = blockIdx.x;
  for (int c = threadIdx.x; c < 1024; c += 256) {
    int i = c >> 1;
    float den = expf(-(float)(2 * i) * 0.0089944739960705f);  // ln(10000)/1024
    float ang = (float)s * den;
    pe[s * 1024 + c] = (c & 1) ? cosf(ang) : sinf(ang);
  }
}

// ---------- embedding * sqrt(d) + PE table; writes fp32 x and bf16 copy ----------
__global__ __launch_bounds__(256) void embed_pe(const int* __restrict__ tgt,
                                                const float* __restrict__ emb,
                                                const float* __restrict__ pe,
                                                float* __restrict__ x,
                                                u16* __restrict__ xbf) {
  int row = blockIdx.x;  // b*1024 + s
  int s = row & 1023;
  int tok = tgt[row];
  float4 e = ((const float4*)(emb + (size_t)tok * 1024))[threadIdx.x];
  float4 p = ((const float4*)(pe + (size_t)s * 1024))[threadIdx.x];
  float4 o;
  o.x = e.x * 32.0f + p.x; o.y = e.y * 32.0f + p.y;
  o.z = e.z * 32.0f + p.z; o.w = e.w * 32.0f + p.w;
  ((float4*)(x + (size_t)row * 1024))[threadIdx.x] = o;
  ushort4 ob;
  ob.x = f2bf(o.x); ob.y = f2bf(o.y); ob.z = f2bf(o.z); ob.w = f2bf(o.w);
  ((ushort4*)(xbf + (size_t)row * 1024))[threadIdx.x] = ob;
}

// ---------- LayerNorm, 2 rows/block (128 lanes x 8 elems per row) ----------
// MODE 1: f32 in -> f32 out; MODE 2: bf16 in -> bf16 out
template <int MODE>
__global__ __launch_bounds__(256) void ln2_k(const float* __restrict__ Xf,
                                             const u16* __restrict__ Xb,
                                             const float* __restrict__ g,
                                             const float* __restrict__ bta,
                                             u16* __restrict__ obf,
                                             float* __restrict__ of) {
  const int t = threadIdx.x;
  const int row = blockIdx.x * 2 + (t >> 7);
  const int c = t & 127;  // 8 elems per lane
  float v[8];
  if (MODE == 1) {
    float4 a = ((const float4*)(Xf + (size_t)row * 1024))[c * 2];
    float4 b4 = ((const float4*)(Xf + (size_t)row * 1024))[c * 2 + 1];
    v[0] = a.x; v[1] = a.y; v[2] = a.z; v[3] = a.w;
    v[4] = b4.x; v[5] = b4.y; v[6] = b4.z; v[7] = b4.w;
  } else {
    u32x4 p = *(const u32x4*)(Xb + (size_t)row * 1024 + c * 8);
#pragma unroll
    for (int i = 0; i < 4; ++i) {
      v[2 * i] = b2f(p[i]);
      v[2 * i + 1] = b2f(p[i] >> 16);
    }
  }
  float s = 0.f, sq = 0.f;
#pragma unroll
  for (int i = 0; i < 8; ++i) { s += v[i]; sq += v[i] * v[i]; }
#pragma unroll
  for (int o = 1; o < 64; o <<= 1) {
    s += __shfl_xor(s, o);
    sq += __shfl_xor(sq, o);
  }
  __shared__ float red[8];
  const int wid = t >> 6;
  if ((t & 63) == 0) { red[wid * 2] = s; red[wid * 2 + 1] = sq; }
  __syncthreads();
  const int base = (t >> 7) * 4;
  s = red[base] + red[base + 2];
  sq = red[base + 1] + red[base + 3];
  float mean = s * (1.0f / 1024.0f);
  float var = sq * (1.0f / 1024.0f) - mean * mean;
  float rstd = rsqrtf(var + 1e-6f);
  float4 g0 = ((const float4*)g)[c * 2], g1 = ((const float4*)g)[c * 2 + 1];
  float4 b0 = ((const float4*)bta)[c * 2], b1 = ((const float4*)bta)[c * 2 + 1];
  float gv[8] = {g0.x, g0.y, g0.z, g0.w, g1.x, g1.y, g1.z, g1.w};
  float bv[8] = {b0.x, b0.y, b0.z, b0.w, b1.x, b1.y, b1.z, b1.w};
  float y[8];
#pragma unroll
  for (int i = 0; i < 8; ++i) y[i] = (v[i] - mean) * rstd * gv[i] + bv[i];
  if (MODE == 1) {
    float4 o0, o1;
    o0.x = y[0]; o0.y = y[1]; o0.z = y[2]; o0.w = y[3];
    o1.x = y[4]; o1.y = y[5]; o1.z = y[6]; o1.w = y[7];
    ((float4*)(of + (size_t)row * 1024))[c * 2] = o0;
    ((float4*)(of + (size_t)row * 1024))[c * 2 + 1] = o1;
  } else {
    u32x4 o;
#pragma unroll
    for (int i = 0; i < 4; ++i)
      o[i] = (u32)f2bf(y[2 * i]) | ((u32)f2bf(y[2 * i + 1]) << 16);
    *(u32x4*)(obf + (size_t)row * 1024 + c * 8) = o;
  }
}

// ---------- GEMM v2c: 3-buffer counted-vmcnt pipeline + XCD swizzle ----------
template <int BM, int EPI>
__global__ __launch_bounds__(256) void gemm2c(
    const u16* __restrict__ A, const u16* __restrict__ Bt,
    const float* __restrict__ bias, float* __restrict__ X,
    u16* __restrict__ Cbf, int N, int K) {
  constexpr int ABYT = BM * 128;
  constexpr int BBYT = 128 * 128;
  constexpr int BUF = ABYT + BBYT;
  constexpr int MF = BM / 32;
  __shared__ __align__(16) char smem[3 * BUF];

  const int tid = threadIdx.x;
  const int w = tid >> 6, l = tid & 63;
  const int lg = l >> 4, lc = l & 15;
  const int nwg = gridDim.x * gridDim.y;  // divisible by 8 in all uses
  int bid = blockIdx.y * gridDim.x + blockIdx.x;
  bid = (bid & 7) * (nwg >> 3) + (bid >> 3);
  const int m0 = (bid / gridDim.x) * BM, n0 = (bid % gridDim.x) * 128;
  const int wr = w >> 1, wc = w & 1;
  const char* Ab = (const char*)A;
  const char* Bb = (const char*)Bt;
  const size_t sA = (size_t)K * 2;

  f32x4 acc[MF][4];
  const f32x4 zv = {0.f, 0.f, 0.f, 0.f};
#pragma unroll
  for (int m = 0; m < MF; ++m)
#pragma unroll
    for (int n = 0; n < 4; ++n) acc[m][n] = zv;

  const int srow = l >> 3;
  const int scol = ((l & 7) ^ srow) << 4;

  auto stage = [&](char* buf, int kt) {
    const size_t kb = (size_t)kt << 7;
#pragma unroll
    for (int i = 0; i < BM / 32; ++i) {
      const int r = i * 32 + w * 8 + srow;
      gld16(Ab + (size_t)(m0 + r) * sA + kb + scol, buf + (i * 4 + w) * 1024 + l * 16);
    }
#pragma unroll
    for (int i = 0; i < 4; ++i) {
      const int r = i * 32 + w * 8 + srow;
      gld16(Bb + (size_t)(n0 + r) * sA + kb + scol,
            buf + ABYT + (i * 4 + w) * 1024 + l * 16);
    }
  };

  char* p0 = smem;
  char* p1 = smem + BUF;
  char* p2 = smem + 2 * BUF;

  stage(p0, 0);
  stage(p1, 1);
  __builtin_amdgcn_sched_barrier(0);
  asm volatile("s_waitcnt vmcnt(6)" ::: "memory");  // tile 0 resident (6 of 12)
  __builtin_amdgcn_s_barrier();
  __builtin_amdgcn_sched_barrier(0);

  const int nkt = K >> 6;
  for (int kt = 0; kt < nkt; ++kt) {
    if (kt + 2 < nkt) stage(p2, kt + 2);
    const char* As = p0;
    const char* Bs = p0 + ABYT;
    __builtin_amdgcn_s_setprio(1);
#pragma unroll
    for (int ks = 0; ks < 2; ++ks) {
      short8 af[MF], bf4[4];
#pragma unroll
      for (int m = 0; m < MF; ++m) {
        int row = wr * (BM / 2) + m * 16 + lc;
        int col = (ks * 64 + (lg << 4)) ^ ((row & 7) << 4);
        af[m] = *(const short8*)(As + row * 128 + col);
      }
#pragma unroll
      for (int n = 0; n < 4; ++n) {
        int row = wc * 64 + n * 16 + lc;
        int col = (ks * 64 + (lg << 4)) ^ ((row & 7) << 4);
        bf4[n] = *(const short8*)(Bs + row * 128 + col);
      }
#pragma unroll
      for (int m = 0; m < MF; ++m)
#pragma unroll
        for (int n = 0; n < 4; ++n) acc[m][n] = mfma16(af[m], bf4[n], acc[m][n]);
    }
    __builtin_amdgcn_s_setprio(0);
    __builtin_amdgcn_sched_barrier(0);
    if (kt + 2 < nkt) {
      asm volatile("s_waitcnt vmcnt(6) lgkmcnt(0)" ::: "memory");
    } else {
      asm volatile("s_waitcnt vmcnt(0) lgkmcnt(0)" ::: "memory");
    }
    __builtin_amdgcn_s_barrier();
    __builtin_amdgcn_sched_barrier(0);
    char* t = p0; p0 = p1; p1 = p2; p2 = t;
  }

  float bv[4];
#pragma unroll
  for (int n = 0; n < 4; ++n) bv[n] = bias[n0 + wc * 64 + n * 16 + lc];

  if (EPI <= 1) {
    u16* ct = (u16*)smem;
#pragma unroll
    for (int m = 0; m < MF; ++m)
#pragma unroll
      for (int n = 0; n < 4; ++n)
#pragma unroll
        for (int r = 0; r < 4; ++r) {
          int row = wr * (BM / 2) + m * 16 + (lg << 2) + r;
          int col = wc * 64 + n * 16 + lc;
          float v = acc[m][n][r] + bv[n];
          if (EPI == 1) v = v > 0.f ? v : 0.f;
          ct[row * 136 + col] = f2bf(v);
        }
    __syncthreads();
#pragma unroll
    for (int j = 0; j < BM / 16; ++j) {
      int c = j * 256 + tid;
      int row = c >> 4, colb = (c & 15) * 8;
      *(short8*)(Cbf + (size_t)(m0 + row) * N + n0 + colb) =
          *(const short8*)(ct + row * 136 + colb);
    }
  } else if (EPI == 2) {
    float* cf = (float*)smem;
#pragma unroll
    for (int m = 0; m < MF; ++m)
#pragma unroll
      for (int n = 0; n < 4; ++n)
#pragma unroll
        for (int r = 0; r < 4; ++r) {
          int row = wr * (BM / 2) + m * 16 + (lg << 2) + r;
          int col = wc * 64 + n * 16 + lc;
          cf[row * 128 + col] = acc[m][n][r] + bv[n];
        }
    __syncthreads();
#pragma unroll
    for (int j = 0; j < BM / 8; ++j) {
      int c = j * 256 + tid;
      int row = c >> 5, colb = (c & 31) * 4;
      size_t idx = (size_t)(m0 + row) * N + n0 + colb;
      float4 s4 = *(const float4*)(cf + row * 128 + colb);
      float4 xv = *(const float4*)(X + idx);
      xv.x += s4.x; xv.y += s4.y; xv.z += s4.z; xv.w += s4.w;
      *(float4*)(X + idx) = xv;
      ushort4 ob;
      ob.x = f2bf(xv.x); ob.y = f2bf(xv.y); ob.z = f2bf(xv.z); ob.w = f2bf(xv.w);
      *(ushort4*)(Cbf + idx) = ob;
    }
  } else {  // EPI == 3: V transposed per head
    u16* ct = (u16*)smem;
#pragma unroll
    for (int m = 0; m < MF; ++m)
#pragma unroll
      for (int n = 0; n < 4; ++n)
#pragma unroll
        for (int r = 0; r < 4; ++r) {
          int row = wr * (BM / 2) + m * 16 + (lg << 2) + r;
          int col = wc * 64 + n * 16 + lc;
          ct[col * 136 + row] = f2bf(acc[m][n][r] + bv[n]);
        }
    __syncthreads();
    const int bb = m0 >> 10, ms = m0 & 1023;
#pragma unroll
    for (int j = 0; j < BM / 16; ++j) {
      int flat = j * 256 + tid;
      int sb = flat & (BM / 8 - 1);
      int col = flat / (BM / 8);
      int n = n0 + col;
      u16* dst = Cbf + (size_t)(((bb << 4) + (n >> 6)) * 64 + (n & 63)) * 1024 + ms + sb * 8;
      *(short8*)dst = *(const short8*)(ct + col * 136 + sb * 8);
    }
  }
}

// ---------- GEMM v3b: 256x256 tile, 8 waves, per-wave 128x64. EPI 1: relu->bf16 ----------
template <int EPI>
__global__ __launch_bounds__(512) void gemm3b(
    const u16* __restrict__ A, const u16* __restrict__ Bt,
    const float* __restrict__ bias, u16* __restrict__ Cbf, int N, int K) {
  constexpr int ABYT = 32768;  // 256 rows x 64k x 2B
  constexpr int BBYT = 32768;
  __shared__ __align__(16) char smem[2 * (ABYT + BBYT)];  // 128KB

  const int tid = threadIdx.x;
  const int w = tid >> 6, l = tid & 63;
  const int lg = l >> 4, lc = l & 15;
  const int nwg = gridDim.x * gridDim.y;  // divisible by 8
  int bid = blockIdx.y * gridDim.x + blockIdx.x;
  bid = (bid & 7) * (nwg >> 3) + (bid >> 3);
  const int m0 = (bid / gridDim.x) * 256, n0 = (bid % gridDim.x) * 256;
  const int wr = w >> 2, wc = w & 3;  // 2 m-waves x 4 n-waves
  const char* Ab = (const char*)A;
  const char* Bb = (const char*)Bt;
  const size_t sA = (size_t)K * 2;

  f32x4 acc[8][4];
  const f32x4 zv = {0.f, 0.f, 0.f, 0.f};
#pragma unroll
  for (int m = 0; m < 8; ++m)
#pragma unroll
    for (int n = 0; n < 4; ++n) acc[m][n] = zv;

  const int srow = l >> 3;
  const int scol = ((l & 7) ^ srow) << 4;

  auto stage = [&](char* buf, int kt) {
    const size_t kb = (size_t)kt << 7;
#pragma unroll
    for (int i = 0; i < 4; ++i) {
      const int r = i * 64 + w * 8 + srow;
      gld16(Ab + (size_t)(m0 + r) * sA + kb + scol, buf + (i * 8 + w) * 1024 + l * 16);
    }
#pragma unroll
    for (int i = 0; i < 4; ++i) {
      const int r = i * 64 + w * 8 + srow;
      gld16(Bb + (size_t)(n0 + r) * sA + kb + scol,
            buf + ABYT + (i * 8 + w) * 1024 + l * 16);
    }
  };

  stage(smem, 0);
  __syncthreads();

  const int nkt = K >> 6;
  int cur = 0;
  for (int kt = 0; kt < nkt; ++kt) {
    char* As = smem + cur * (ABYT + BBYT);
    char* Bs = As + ABYT;
    if (kt + 1 < nkt) stage(smem + (cur ^ 1) * (ABYT + BBYT), kt + 1);
    __builtin_amdgcn_s_setprio(1);
#pragma unroll
    for (int ks = 0; ks < 2; ++ks) {
      short8 bf4[4];
#pragma unroll
      for (int n = 0; n < 4; ++n) {
        int row = wc * 64 + n * 16 + lc;
        int col = (ks * 64 + (lg << 4)) ^ ((row & 7) << 4);
        bf4[n] = *(const short8*)(Bs + row * 128 + col);
      }
#pragma unroll
      for (int m = 0; m < 8; ++m) {
        int row = wr * 128 + m * 16 + lc;
        int col = (ks * 64 + (lg << 4)) ^ ((row & 7) << 4);
        short8 af = *(const short8*)(As + row * 128 + col);
#pragma unroll
        for (int n = 0; n < 4; ++n) acc[m][n] = mfma16(af, bf4[n], acc[m][n]);
      }
    }
    __builtin_amdgcn_s_setprio(0);
    __syncthreads();
    cur ^= 1;
  }

  // ---- epilogue: two half-tile LDS passes ([128][264] u16), coalesced stores ----
  float bv[4];
#pragma unroll
  for (int n = 0; n < 4; ++n) bv[n] = bias[n0 + wc * 64 + n * 16 + lc];
  u16* ct = (u16*)smem;
#pragma unroll
  for (int h = 0; h < 2; ++h) {
    __syncthreads();
    if (wr == h) {
#pragma unroll
      for (int m = 0; m < 8; ++m)
#pragma unroll
        for (int n = 0; n < 4; ++n)
#pragma unroll
          for (int r = 0; r < 4; ++r) {
            int row = m * 16 + (lg << 2) + r;  // 0..127 within half
            int col = wc * 64 + n * 16 + lc;
            float v = acc[m][n][r] + bv[n];
            if (EPI == 1) v = v > 0.f ? v : 0.f;
            ct[row * 264 + col] = f2bf(v);
          }
    }
    __syncthreads();
#pragma unroll
    for (int j = 0; j < 8; ++j) {  // 128 rows x 32 col-blocks = 4096 / 512 threads
      int c = j * 512 + tid;
      int row = c >> 5, colb = (c & 31) * 8;
      *(short8*)(Cbf + (size_t)(m0 + h * 128 + row) * N + n0 + colb) =
          *(const short8*)(ct + row * 264 + colb);
    }
  }
}

// ---------- GEMM v3q: 256x256 tile over N=3072 (QKV fused) ----------
__global__ __launch_bounds__(512) void gemm3q(
    const u16* __restrict__ A, const u16* __restrict__ Bt,
    const float* __restrict__ bias, u16* __restrict__ Cqk, u16* __restrict__ Vt, int K) {
  constexpr int ABYT = 32768;
  constexpr int BBYT = 32768;
  __shared__ __align__(16) char smem[2 * (ABYT + BBYT)];  // 128KB

  const int tid = threadIdx.x;
  const int w = tid >> 6, l = tid & 63;
  const int lg = l >> 4, lc = l & 15;
  const int nwg = gridDim.x * gridDim.y;  // 12*16 = 192, divisible by 8
  int bid = blockIdx.y * gridDim.x + blockIdx.x;
  bid = (bid & 7) * (nwg >> 3) + (bid >> 3);
  const int m0 = (bid / gridDim.x) * 256, n0 = (bid % gridDim.x) * 256;
  const int wr = w >> 2, wc = w & 3;
  const char* Ab = (const char*)A;
  const char* Bb = (const char*)Bt;
  const size_t sA = (size_t)K * 2;

  f32x4 acc[8][4];
  const f32x4 zv = {0.f, 0.f, 0.f, 0.f};
#pragma unroll
  for (int m = 0; m < 8; ++m)
#pragma unroll
    for (int n = 0; n < 4; ++n) acc[m][n] = zv;

  const int srow = l >> 3;
  const int scol = ((l & 7) ^ srow) << 4;

  auto stage = [&](char* buf, int kt) {
    const size_t kb = (size_t)kt << 7;
#pragma unroll
    for (int i = 0; i < 4; ++i) {
      const int r = i * 64 + w * 8 + srow;
      gld16(Ab + (size_t)(m0 + r) * sA + kb + scol, buf + (i * 8 + w) * 1024 + l * 16);
    }
#pragma unroll
    for (int i = 0; i < 4; ++i) {
      const int r = i * 64 + w * 8 + srow;
      gld16(Bb + (size_t)(n0 + r) * sA + kb + scol,
            buf + ABYT + (i * 8 + w) * 1024 + l * 16);
    }
  };

  stage(smem, 0);
  __syncthreads();

  const int nkt = K >> 6;
  int cur = 0;
  for (int kt = 0; kt < nkt; ++kt) {
    char* As = smem + cur * (ABYT + BBYT);
    char* Bs = As + ABYT;
    if (kt + 1 < nkt) stage(smem + (cur ^ 1) * (ABYT + BBYT), kt + 1);
    __builtin_amdgcn_s_setprio(1);
#pragma unroll
    for (int ks = 0; ks < 2; ++ks) {
      short8 bf4[4];
#pragma unroll
      for (int n = 0; n < 4; ++n) {
        int row = wc * 64 + n * 16 + lc;
        int col = (ks * 64 + (lg << 4)) ^ ((row & 7) << 4);
        bf4[n] = *(const short8*)(Bs + row * 128 + col);
      }
#pragma unroll
      for (int m = 0; m < 8; ++m) {
        int row = wr * 128 + m * 16 + lc;
        int col = (ks * 64 + (lg << 4)) ^ ((row & 7) << 4);
        short8 af = *(const short8*)(As + row * 128 + col);
#pragma unroll
        for (int n = 0; n < 4; ++n) acc[m][n] = mfma16(af, bf4[n], acc[m][n]);
      }
    }
    __builtin_amdgcn_s_setprio(0);
    __syncthreads();
    cur ^= 1;
  }

  float bv[4];
#pragma unroll
  for (int n = 0; n < 4; ++n) bv[n] = bias[n0 + wc * 64 + n * 16 + lc];
  u16* ct = (u16*)smem;

  if (n0 < 2048) {
    // Q/K region: standard bf16 store, row stride 2048
#pragma unroll
    for (int h = 0; h < 2; ++h) {
      __syncthreads();
      if (wr == h) {
#pragma unroll
        for (int m = 0; m < 8; ++m)
#pragma unroll
          for (int n = 0; n < 4; ++n)
#pragma unroll
            for (int r = 0; r < 4; ++r) {
              int row = m * 16 + (lg << 2) + r;
              int col = wc * 64 + n * 16 + lc;
              ct[row * 264 + col] = f2bf(acc[m][n][r] + bv[n]);
            }
      }
      __syncthreads();
#pragma unroll
      for (int j = 0; j < 8; ++j) {
        int c = j * 512 + tid;
        int row = c >> 5, colb = (c & 31) * 8;
        *(short8*)(Cqk + (size_t)(m0 + h * 128 + row) * 2048 + n0 + colb) =
            *(const short8*)(ct + row * 264 + colb);
      }
    }
  } else {
    // V region: per-head transpose Vt[(b*16+h)*64+d][s]
    const int bb = m0 >> 10, ms = m0 & 1023;
#pragma unroll
    for (int h = 0; h < 2; ++h) {
      __syncthreads();
      if (wr == h) {
#pragma unroll
        for (int m = 0; m < 8; ++m)
#pragma unroll
          for (int n = 0; n < 4; ++n)
#pragma unroll
            for (int r = 0; r < 4; ++r) {
              int row = m * 16 + (lg << 2) + r;  // s-offset within half, 0..127
              int col = wc * 64 + n * 16 + lc;   // 0..255
              ct[col * 136 + row] = f2bf(acc[m][n][r] + bv[n]);
            }
      }
      __syncthreads();
#pragma unroll
      for (int j = 0; j < 8; ++j) {  // 256 cols x 16 row-chunks = 4096 / 512
        int flat = j * 512 + tid;
        int col = flat >> 4, sb = flat & 15;
        int n = n0 + col - 2048;  // V col in [0,1024)
        u16* dst = Vt + (size_t)(((bb << 4) + (n >> 6)) * 64 + (n & 63)) * 1024 +
                   ms + h * 128 + sb * 8;
        *(short8*)dst = *(const short8*)(ct + col * 136 + sb * 8);
      }
    }
  }
}

// ---------- flash attention v5: 8 waves/block share K/V staging ----------
template <bool CAUSAL>
__global__ __launch_bounds__(512) void attn_lds(
    const u16* __restrict__ Qp, int sQ, const u16* __restrict__ Kp, int sK,
    const u16* __restrict__ Vt, const int* __restrict__ tgt,
    u16* __restrict__ Out) {
  __shared__ __align__(16) char smem[2][32768];
  const int tid = threadIdx.x;
  const int w = tid >> 6, l = tid & 63;
  const int bh = blockIdx.x & 63;
  const int p = blockIdx.x >> 6;  // in [0,4)
  const int qt = CAUSAL ? ((w < 4) ? (p * 4 + w) : (31 - (p * 4 + (w - 4))))
                        : (p * 8 + w);
  const int b = bh >> 4, h = bh & 15;
  const int lq = l & 31, hi = l >> 5;
  const int q0 = qt * 32;

  const char* Kc = (const char*)(Kp + (size_t)b * 1024 * sK + h * 64);
  const char* Vc = (const char*)(Vt + (size_t)bh * 64 * 1024);
  const u16* Qh = Qp + (size_t)b * 1024 * sQ + h * 64;

  short8 qb[4];
  {
    const u16* qrow = Qh + (size_t)(q0 + lq) * sQ + hi * 8;
#pragma unroll
    for (int c = 0; c < 4; ++c) qb[c] = *(const short8*)(qrow + c * 16);
  }

  bool row_ok = true;
  int my_nkt = 16;                       // in 64-key tiles
  int blk_nst = CAUSAL ? (8 - p) : 8;    // super-tiles (128 keys)
  if (CAUSAL) {
    row_ok = (tgt[b * 1024 + q0 + lq] != 1);
    bool anypad_w = __any(!row_ok);
    __shared__ int s_pad;
    if (tid == 0) s_pad = 0;
    __syncthreads();
    if (anypad_w && l == 0) s_pad = 1;
    __syncthreads();
    // pad row => all keys masked => uniform softmax over all 1024 keys
    if (s_pad) { my_nkt = 16; blk_nst = 8; }
    else my_nkt = (qt >> 1) + 1;
  }

  const int srow = l >> 3;
  const int scol = ((l & 7) ^ srow) << 4;
  auto stage = [&](int buf, int st) {
    const int k0 = st * 128;
    char* Ks = smem[buf];
    char* Vs = smem[buf] + 16384;
    const int r = w * 8 + srow;  // 8 waves cover rows 0..63
#pragma unroll
    for (int t2 = 0; t2 < 2; ++t2) {
      gld16(Kc + (size_t)(k0 + t2 * 64 + r) * sK * 2 + scol, Ks + t2 * 8192 + r * 128);
      gld16(Vc + (size_t)r * 2048 + (size_t)(k0 + t2 * 64) * 2 + scol,
            Vs + t2 * 8192 + r * 128);
    }
  };

  float m = -3.0e38f, lsum = 0.f;
  f32x16 oacc[2];
#pragma unroll
  for (int r = 0; r < 16; ++r) { oacc[0][r] = 0.f; oacc[1][r] = 0.f; }

  stage(0, 0);
  __syncthreads();
  int cur = 0;

  for (int st = 0; st < blk_nst; ++st) {
    if (st + 1 < blk_nst) stage(cur ^ 1, st + 1);
#pragma unroll
    for (int t2 = 0; t2 < 2; ++t2) {
      const int t64 = st * 2 + t2;
      if (t64 < my_nkt) {
        const char* Ks = smem[cur] + t2 * 8192;
        const char* Vs = smem[cur] + 16384 + t2 * 8192;
        const int k0 = t64 * 64;
        // ---- QK^T ----
        f32x16 stt[2];
        __builtin_amdgcn_s_setprio(1);
#pragma unroll
        for (int s = 0; s < 2; ++s) {
          const int row = s * 32 + lq;
          const int swz = (row & 7) << 4;
          f32x16 a;
#pragma unroll
          for (int r = 0; r < 16; ++r) a[r] = 0.f;
#pragma unroll
          for (int c = 0; c < 4; ++c) {
            short8 kb = *(const short8*)(Ks + row * 128 + ((c * 32 + hi * 16) ^ swz));
            a = mfma32(kb, qb[c], a);
          }
          stt[s] = a;
        }
        __builtin_amdgcn_s_setprio(0);
        // ---- masking ----
        if (CAUSAL) {
#pragma unroll
          for (int s = 0; s < 2; ++s) {
            if (!row_ok || (k0 + s * 32 + 31 > q0)) {
#pragma unroll
              for (int r = 0; r < 16; ++r) {
                int kg = k0 + s * 32 + (r & 3) + 8 * (r >> 2) + 4 * hi;
                bool ok = row_ok && (kg <= q0 + lq);
                if (!ok) stt[s][r] = -1e9f;
              }
            }
          }
        }
        // ---- tile max ----
        float tm;
        {
          float v[16];
#pragma unroll
          for (int r = 0; r < 16; ++r) v[r] = fmaxf(stt[0][r], stt[1][r]);
#pragma unroll
          for (int w2 = 8; w2 >= 1; w2 >>= 1)
#pragma unroll
            for (int r = 0; r < w2; ++r) v[r] = fmaxf(v[r], v[r + w2]);
          tm = v[0];
        }
        tm = fmaxf(tm, __shfl_xor(tm, 32));
        // ---- defer-max rescale (rare) ----
        if (!__all(tm <= m + 8.0f)) {
          float mn = fmaxf(m, tm);
          float alpha = __expf(m - mn);
          lsum *= alpha;
          m = mn;
#pragma unroll
          for (int r = 0; r < 16; ++r) {
            int crow = (r & 3) + 8 * (r >> 2) + 4 * hi;
            float av = __shfl(alpha, crow);
            oacc[0][r] *= av;
            oacc[1][r] *= av;
          }
        }
        // ---- exp + row-sum ----
        float tsa0 = 0.f, tsa1 = 0.f, tsa2 = 0.f, tsa3 = 0.f;
#pragma unroll
        for (int s = 0; s < 2; ++s) {
#pragma unroll
          for (int r = 0; r < 16; ++r) {
            float e = __expf(stt[s][r] - m);
            stt[s][r] = e;
            if ((r & 3) == 0) tsa0 += e;
            else if ((r & 3) == 1) tsa1 += e;
            else if ((r & 3) == 2) tsa2 += e;
            else tsa3 += e;
          }
        }
        float ts = (tsa0 + tsa1) + (tsa2 + tsa3);
        ts += __shfl_xor(ts, 32);
        lsum += ts;
        // ---- pack P -> bf16 A-frags ----
        short8 pa[4];
#pragma unroll
        for (int s = 0; s < 2; ++s) {
          u32 cc[8];
#pragma unroll
          for (int t = 0; t < 4; ++t) {
            cc[2 * t]     = cvtpk(stt[s][4 * t + 0], stt[s][4 * t + 1]);
            cc[2 * t + 1] = cvtpk(stt[s][4 * t + 2], stt[s][4 * t + 3]);
          }
          plswap(cc[0], cc[2]);
          plswap(cc[1], cc[3]);
          plswap(cc[4], cc[6]);
          plswap(cc[5], cc[7]);
          u32x4 w0 = {cc[0], cc[1], cc[2], cc[3]};
          u32x4 w1 = {cc[4], cc[5], cc[6], cc[7]};
          pa[2 * s]     = __builtin_bit_cast(short8, w0);
          pa[2 * s + 1] = __builtin_bit_cast(short8, w1);
        }
        // ---- PV ----
        __builtin_amdgcn_s_setprio(1);
#pragma unroll
        for (int dt = 0; dt < 2; ++dt) {
          const int row = dt * 32 + lq;
          const int swz = (row & 7) << 4;
#pragma unroll
          for (int c = 0; c < 4; ++c) {
            short8 vb = *(const short8*)(Vs + row * 128 + ((c * 32 + hi * 16) ^ swz));
            oacc[dt] = mfma32(pa[c], vb, oacc[dt]);
          }
        }
        __builtin_amdgcn_s_setprio(0);
      }
    }
    __syncthreads();
    cur ^= 1;
  }

#pragma unroll
  for (int r = 0; r < 16; ++r) {
    int crow = (r & 3) + 8 * (r >> 2) + 4 * hi;
    float lv = __shfl(lsum, crow);
    float linv = 1.0f / lv;
    int qg = q0 + crow;
    size_t base = ((size_t)b * 1024 + qg) * 1024 + h * 64 + lq;
    Out[base] = f2bf(oacc[0][r] * linv);
    Out[base + 32] = f2bf(oacc[1][r] * linv);
  }
}

// =====================================================================
extern "C" void kernel_launch(void* const* d_in, const int* in_sizes, int n_in,
                              void* d_out, int out_size, void* d_ws, size_t ws_size,
                              hipStream_t stream) {
  const int* tgt = (const int*)d_in[0];
  const float* memory = (const float*)d_in[1];
  const float* emb = (const float*)d_in[2];
  const float* ff_w1 = (const float*)d_in[3];
  const float* ff_b1 = (const float*)d_in[4];
  const float* ff_w2 = (const float*)d_in[5];
  const float* ff_b2 = (const float*)d_in[6];
  const float* ln_g = (const float*)d_in[7];
  const float* ln_b = (const float*)d_in[8];
  const float* sa_wq = (const float*)d_in[9];
  const float* sa_bq = (const float*)d_in[10];
  const float* sa_wk = (const float*)d_in[11];
  const float* sa_bk = (const float*)d_in[12];
  const float* sa_wv = (const float*)d_in[13];
  const float* sa_bv = (const float*)d_in[14];
  const float* sa_wo = (const float*)d_in[15];
  const float* sa_bo = (const float*)d_in[16];
  const float* xa_wq = (const float*)d_in[17];
  const float* xa_bq = (const float*)d_in[18];
  const float* xa_wk = (const float*)d_in[19];
  const float* xa_bk = (const float*)d_in[20];
  const float* xa_wv = (const float*)d_in[21];
  const float* xa_bv = (const float*)d_in[22];
  const float* xa_wo = (const float*)d_in[23];
  const float* xa_bo = (const float*)d_in[24];

  char* ws = (char*)d_ws;
  size_t off = 0;
  auto alloc = [&](size_t bytes) {
    char* p = ws + off;
    off += (bytes + 255) & ~(size_t)255;
    return p;
  };
  float* x   = (float*)alloc(4096ull * 1024 * 4);
  u16* xbf   = (u16*)alloc(4096ull * 1024 * 2);
  u16* nbf   = (u16*)alloc(4096ull * 1024 * 2);
  u16* qkv   = (u16*)alloc(4096ull * 2048 * 2);
  u16* q2    = (u16*)alloc(4096ull * 1024 * 2);
  u16* attn  = (u16*)alloc(4096ull * 1024 * 2);
  u16* vt    = (u16*)alloc(64ull * 64 * 1024 * 2);
  u16* kx    = (u16*)alloc(4096ull * 1024 * 2);
  u16* vtx   = (u16*)alloc(64ull * 64 * 1024 * 2);
  u16* h1    = (u16*)alloc(4096ull * 4096 * 2);
  u16* memb  = (u16*)alloc(4096ull * 1024 * 2);
  u16* w_qkv = (u16*)alloc(3072ull * 1024 * 2);
  u16* w_sao = (u16*)alloc(1024ull * 1024 * 2);
  u16* w_xaq = (u16*)alloc(1024ull * 1024 * 2);
  u16* w_xak = (u16*)alloc(1024ull * 1024 * 2);
  u16* w_xav = (u16*)alloc(1024ull * 1024 * 2);
  u16* w_xao = (u16*)alloc(1024ull * 1024 * 2);
  u16* w_ff1 = (u16*)alloc(4096ull * 1024 * 2);
  u16* w_ff2 = (u16*)alloc(1024ull * 4096 * 2);
  float* b_qkv = (float*)alloc(3072 * 4);
  float* b_xaq = (float*)alloc(1024 * 4);
  float* pe    = (float*)alloc(1024ull * 1024 * 4);

  dim3 blk(256);
  dim3 b32(32, 8);
  const float QS = 0.125f;  // 1/sqrt(dk), folded into wq/bq

  // ---- setup: batched weight conversion/transpose (shared across the 4 stacks) ----
  W8 wp;
  wp.src[0] = sa_wq; wp.dst[0] = w_qkv;               wp.scale[0] = QS;
  wp.src[1] = sa_wk; wp.dst[1] = w_qkv + 1024 * 1024; wp.scale[1] = 1.f;
  wp.src[2] = sa_wv; wp.dst[2] = w_qkv + 2048 * 1024; wp.scale[2] = 1.f;
  wp.src[3] = sa_wo; wp.dst[3] = w_sao;               wp.scale[3] = 1.f;
  wp.src[4] = xa_wq; wp.dst[4] = w_xaq;               wp.scale[4] = QS;
  wp.src[5] = xa_wk; wp.dst[5] = w_xak;               wp.scale[5] = 1.f;
  wp.src[6] = xa_wv; wp.dst[6] = w_xav;               wp.scale[6] = 1.f;
  wp.src[7] = xa_wo; wp.dst[7] = w_xao;               wp.scale[7] = 1.f;
  transpose_wt8<<<dim3(32, 32, 8), b32, 0, stream>>>(wp);
  transpose_wt<<<dim3(128, 32), b32, 0, stream>>>(ff_w1, w_ff1, 1024, 4096, 1.f);
  transpose_wt<<<dim3(32, 128), b32, 0, stream>>>(ff_w2, w_ff2, 4096, 1024, 1.f);
  prep_bias<<<16, blk, 0, stream>>>(sa_bq, sa_bk, sa_bv, xa_bq, b_qkv, b_xaq, QS);
  cvt_bf16<<<4096, blk, 0, stream>>>(memory, memb);
  pe_k<<<1024, blk, 0, stream>>>(pe);
  embed_pe<<<4096, blk, 0, stream>>>(tgt, emb, pe, x, xbf);

  // ---- hoisted cross-attention K/V (identical in all 4 stacks) ----
  gemm2c<64, 0><<<dim3(8, 64), blk, 0, stream>>>(memb, w_xak, xa_bk, nullptr, kx, 1024, 1024);
  gemm2c<64, 3><<<dim3(8, 64), blk, 0, stream>>>(memb, w_xav, xa_bv, nullptr, vtx, 1024, 1024);

  for (int layer = 0; layer < 4; ++layer) {
    // self-attention block (fused QKV + V-transpose)
    ln2_k<2><<<2048, blk, 0, stream>>>(nullptr, xbf, ln_g, ln_b, nbf, nullptr);
    gemm3q<<<dim3(12, 16), dim3(512), 0, stream>>>(nbf, w_qkv, b_qkv, qkv, vt, 1024);
    attn_lds<true><<<256, dim3(512), 0, stream>>>(qkv, 2048, qkv + 1024, 2048, vt, tgt, attn);
    gemm2c<64, 2><<<dim3(8, 64), blk, 0, stream>>>(attn, w_sao, sa_bo, x, xbf, 1024, 1024);
    // cross-attention block
    ln2_k<2><<<2048, blk, 0, stream>>>(nullptr, xbf, ln_g, ln_b, nbf, nullptr);
    gemm2c<64, 0><<<dim3(8, 64), blk, 0, stream>>>(nbf, w_xaq, b_xaq, nullptr, q2, 1024, 1024);
    attn_lds<false><<<256, dim3(512), 0, stream>>>(q2, 1024, kx, 1024, vtx, nullptr, attn);
    gemm2c<64, 2><<<dim3(8, 64), blk, 0, stream>>>(attn, w_xao, xa_bo, x, xbf, 1024, 1024);
    // FFN block
    ln2_k<2><<<2048, blk, 0, stream>>>(nullptr, xbf, ln_g, ln_b, nbf, nullptr);
    gemm3b<1><<<dim3(16, 16), dim3(512), 0, stream>>>(nbf, w_ff1, ff_b1, h1, 4096, 1024);
    gemm2c<64, 2><<<dim3(8, 64), blk, 0, stream>>>(h1, w_ff2, ff_b2, x, xbf, 1024, 4096);
  }
  ln2_k<1><<<2048, blk, 0, stream>>>(x, nullptr, ln_g, ln_b, nullptr, (float*)d_out);
}